// Round 6
// baseline (135.717 us; speedup 1.0000x reference)
//
#include <hip/hip_runtime.h>
#include <hip/hip_bf16.h>
#include <math.h>

#define BB 64
#define LL 2048
#define HH 512
#define EE 512
#define VV 32000
#define H3 1536

typedef __attribute__((ext_vector_type(8))) __bf16 bf16x8;
typedef __attribute__((ext_vector_type(4))) float f32x4;

__device__ __forceinline__ void ld8(const float* __restrict__ p, float* v) {
  float4 a = *(const float4*)p;
  float4 b = *(const float4*)(p + 4);
  v[0]=a.x; v[1]=a.y; v[2]=a.z; v[3]=a.w;
  v[4]=b.x; v[5]=b.y; v[6]=b.z; v[7]=b.w;
}
__device__ __forceinline__ void ld16(const float* __restrict__ p, float* v) {
  ld8(p, v); ld8(p + 8, v + 8);
}
__device__ __forceinline__ float wsum(float v) {
#pragma unroll
  for (int off = 32; off; off >>= 1) v += __shfl_xor(v, off);
  return v;
}
__device__ __forceinline__ unsigned short f2bf(float f) {
  unsigned int u = __float_as_uint(f);
  u = (u + 0x7FFFu + ((u >> 16) & 1u)) >> 16;
  return (unsigned short)u;
}

// K1: gi = x @ W_ih^T + b_ih, gh = h @ W_hh^T + b_hh  (proven)
__global__ __launch_bounds__(256) void k1_gates(
    const int* __restrict__ seq, const float* __restrict__ h,
    const float* __restrict__ emb, const float* __restrict__ Wih,
    const float* __restrict__ Whh, const float* __restrict__ bih,
    const float* __restrict__ bhh, float* __restrict__ gi,
    float* __restrict__ gh) {
  int lane = threadIdx.x & 63;
  int wid = blockIdx.x * 4 + (threadIdx.x >> 6);  // 0..1535
  int jp = wid >> 1, bh = wid & 1;
  int j0 = jp * 2;
  float wih[2][8], whh[2][8];
#pragma unroll
  for (int r = 0; r < 2; ++r) {
    ld8(Wih + (size_t)(j0 + r) * EE + lane * 8, wih[r]);
    ld8(Whh + (size_t)(j0 + r) * HH + lane * 8, whh[r]);
  }
  for (int b = bh * 32; b < bh * 32 + 32; ++b) {
    int idx = seq[b];
    float xv[8], hv[8];
    ld8(emb + (size_t)idx * EE + lane * 8, xv);
    ld8(h + b * HH + lane * 8, hv);
#pragma unroll
    for (int r = 0; r < 2; ++r) {
      float di = 0.f, dh = 0.f;
#pragma unroll
      for (int i = 0; i < 8; ++i) {
        di += wih[r][i] * xv[i];
        dh += whh[r][i] * hv[i];
      }
      di = wsum(di);
      dh = wsum(dh);
      if (lane == 0) {
        gi[b * H3 + j0 + r] = di + bih[j0 + r];
        gh[b * H3 + j0 + r] = dh + bhh[j0 + r];
      }
    }
  }
}

// K3': h_new recompute (per-block, redundant) + fused scores +
// online-softmax partial context, 4-row-batched loads for MLP.
// grid (16 ch, 64 b) x 256 threads. ch==0 wave 0 also writes
// out1 / out3 / cat[:, :512].
__global__ __launch_bounds__(256) void k3_attn(
    const float* __restrict__ enc, const float* __restrict__ gi,
    const float* __restrict__ gh, const float* __restrict__ h,
    const float* __restrict__ feed, float* __restrict__ cat,
    float* __restrict__ out1, float* __restrict__ out3,
    float* __restrict__ scores, float* __restrict__ pm,
    float* __restrict__ ps, float* __restrict__ pc) {
  int b = blockIdx.y, ch = blockIdx.x;
  int w = threadIdx.x >> 6, lane = threadIdx.x & 63;
  int k0 = lane * 8;

  // recompute h_new[b][k0..k0+7] (identical across the 4 waves)
  float hv[8];
  {
    float gr[8], gz[8], gn[8], hr[8], hz[8], hn_[8], hh[8];
    const float* gib = gi + b * H3;
    const float* ghb = gh + b * H3;
    ld8(gib + k0, gr); ld8(gib + 512 + k0, gz); ld8(gib + 1024 + k0, gn);
    ld8(ghb + k0, hr); ld8(ghb + 512 + k0, hz); ld8(ghb + 1024 + k0, hn_);
    ld8(h + b * HH + k0, hh);
#pragma unroll
    for (int i = 0; i < 8; ++i) {
      float r = 1.f / (1.f + __expf(-(gr[i] + hr[i])));
      float z = 1.f / (1.f + __expf(-(gz[i] + hz[i])));
      float n = tanhf(gn[i] + r * hn_[i]);
      hv[i] = (1.f - z) * n + z * hh[i];
    }
    if (ch == 0 && w == 0) {
      float fv[8];
      ld8(feed + b * HH + k0, fv);
#pragma unroll
      for (int i = 0; i < 8; ++i) {
        out1[b * HH + k0 + i] = hv[i];
        cat[b * 1024 + k0 + i] = hv[i];
        out3[b * HH + k0 + i] = fv[i];
      }
    }
  }

  float m = -INFINITY, s = 0.f, c[8];
#pragma unroll
  for (int j = 0; j < 8; ++j) c[j] = 0.f;
  const float* eb = enc + ((size_t)b * LL + ch * 128) * HH;
  for (int it = 0; it < 8; ++it) {
    float ev[4][8], d[4];
#pragma unroll
    for (int q = 0; q < 4; ++q) {
      int l = w + (it * 4 + q) * 4;
      ld8(eb + (size_t)l * HH + k0, ev[q]);
    }
#pragma unroll
    for (int q = 0; q < 4; ++q) {
      float dd = 0.f;
#pragma unroll
      for (int j = 0; j < 8; ++j) dd += hv[j] * ev[q][j];
      d[q] = wsum(dd);
    }
    if (lane == 0) {
#pragma unroll
      for (int q = 0; q < 4; ++q)
        scores[b * LL + ch * 128 + w + (it * 4 + q) * 4] = d[q];
    }
    float g = fmaxf(fmaxf(d[0], d[1]), fmaxf(d[2], d[3]));
    if (g > m) {  // wave-uniform
      float sc = __expf(m - g);
      s *= sc;
#pragma unroll
      for (int j = 0; j < 8; ++j) c[j] *= sc;
      m = g;
    }
#pragma unroll
    for (int q = 0; q < 4; ++q) {
      float wq = __expf(d[q] - m);
      s += wq;
#pragma unroll
      for (int j = 0; j < 8; ++j) c[j] += wq * ev[q][j];
    }
  }
  __shared__ float sm[4], ssum[4];
  __shared__ float scx[4][512];
  if (lane == 0) { sm[w] = m; ssum[w] = s; }
#pragma unroll
  for (int j = 0; j < 8; ++j) scx[w][k0 + j] = c[j];
  __syncthreads();
  float mb = fmaxf(fmaxf(sm[0], sm[1]), fmaxf(sm[2], sm[3]));
  int t = threadIdx.x;
  if (t == 0) {
    float sb = 0.f;
#pragma unroll
    for (int w2 = 0; w2 < 4; ++w2) sb += ssum[w2] * __expf(sm[w2] - mb);
    pm[b * 16 + ch] = mb;
    ps[b * 16 + ch] = sb;
  }
  for (int k = t; k < 512; k += 256) {
    float v = 0.f;
#pragma unroll
    for (int w2 = 0; w2 < 4; ++w2) v += scx[w2][k] * __expf(sm[w2] - mb);
    pc[(size_t)(b * 16 + ch) * 512 + k] = v;
  }
}

// K45: per-batch combine -> ctx (cat[:,512:]) AND attn-weights output.
__global__ __launch_bounds__(256) void k45_ctx(
    const float* __restrict__ pm, const float* __restrict__ ps,
    const float* __restrict__ pc, const float* __restrict__ scores,
    float* __restrict__ cat, float* __restrict__ out2) {
  int b = blockIdx.x;
  int tid = threadIdx.x;
  float mb = -INFINITY;
#pragma unroll
  for (int ch = 0; ch < 16; ++ch) mb = fmaxf(mb, pm[b * 16 + ch]);
  float e[16];
  float den = 0.f;
#pragma unroll
  for (int ch = 0; ch < 16; ++ch) {
    e[ch] = __expf(pm[b * 16 + ch] - mb);
    den += ps[b * 16 + ch] * e[ch];
  }
  for (int k = tid; k < 512; k += 256) {
    float v = 0.f;
#pragma unroll
    for (int ch = 0; ch < 16; ++ch)
      v += pc[(size_t)(b * 16 + ch) * 512 + k] * e[ch];
    cat[b * 1024 + 512 + k] = v / den;
  }
  float inv = 1.f / den;
  for (int t = tid; t < LL; t += 256) {
    out2[b * LL + t] = __expf(scores[b * LL + t] - mb) * inv;
  }
}

// K6: concat_output = tanh([h_new, ctx] @ W_concat^T + b_concat) -> bf16
__global__ __launch_bounds__(256) void k6_concat(
    const float* __restrict__ cat, const float* __restrict__ Wc,
    const float* __restrict__ bc, unsigned short* __restrict__ co_bf) {
  int lane = threadIdx.x & 63;
  int wid = blockIdx.x * 4 + (threadIdx.x >> 6);  // 0..4095
  int k = wid >> 3, bg = wid & 7;
  float wv[16];
  ld16(Wc + (size_t)k * 1024 + lane * 16, wv);
  float bk = bc[k];
  for (int b = bg * 8; b < bg * 8 + 8; ++b) {
    float cv[16];
    ld16(cat + b * 1024 + lane * 16, cv);
    float d = 0.f;
#pragma unroll
    for (int i = 0; i < 16; ++i) d += wv[i] * cv[i];
    d = wsum(d);
    if (lane == 0) co_bf[b * HH + k] = f2bf(tanhf(d + bk));
  }
}

// K7 (MFMA, proven): out0 = co @ W_out^T + b_out.
__global__ __launch_bounds__(256) void k7_out(
    const unsigned short* __restrict__ co_bf, const float* __restrict__ Wo,
    const float* __restrict__ bo, float* __restrict__ out0) {
  int t = threadIdx.x;
  int lane = t & 63, w = t >> 6;
  int v0 = blockIdx.x * 64 + w * 16;
  int l15 = lane & 15;
  int kbase = (lane >> 4) * 8;
  int vrow = v0 + l15;
  const float* wrow = Wo + (size_t)vrow * HH;

  f32x4 acc[4];
#pragma unroll
  for (int j = 0; j < 4; ++j) acc[j] = (f32x4){0.f, 0.f, 0.f, 0.f};

  for (int ks = 0; ks < HH; ks += 32) {
    int k = ks + kbase;
    float4 wa = *(const float4*)(wrow + k);
    float4 wb = *(const float4*)(wrow + k + 4);
    union { unsigned short u[8]; bf16x8 v; } B;
    B.u[0] = f2bf(wa.x); B.u[1] = f2bf(wa.y);
    B.u[2] = f2bf(wa.z); B.u[3] = f2bf(wa.w);
    B.u[4] = f2bf(wb.x); B.u[5] = f2bf(wb.y);
    B.u[6] = f2bf(wb.z); B.u[7] = f2bf(wb.w);
#pragma unroll
    for (int j = 0; j < 4; ++j) {
      bf16x8 A = *(const bf16x8*)(co_bf + (size_t)(j * 16 + l15) * HH + k);
      acc[j] = __builtin_amdgcn_mfma_f32_16x16x32_bf16(A, B.v, acc[j], 0, 0, 0);
    }
  }

  float bias = bo[vrow];
#pragma unroll
  for (int j = 0; j < 4; ++j) {
    int b0 = j * 16 + (lane >> 4) * 4;
#pragma unroll
    for (int r = 0; r < 4; ++r) {
      out0[(size_t)(b0 + r) * VV + vrow] = acc[j][r] + bias;
    }
  }
}

extern "C" void kernel_launch(void* const* d_in, const int* in_sizes, int n_in,
                              void* d_out, int out_size, void* d_ws,
                              size_t ws_size, hipStream_t stream) {
  const int* seq = (const int*)d_in[0];
  const float* last_hidden = (const float*)d_in[1];
  const float* enc = (const float*)d_in[2];
  // d_in[3] encoder_labels unused
  const float* feed = (const float*)d_in[4];
  const float* emb = (const float*)d_in[5];
  const float* Wih = (const float*)d_in[6];
  const float* Whh = (const float*)d_in[7];
  const float* bih = (const float*)d_in[8];
  const float* bhh = (const float*)d_in[9];
  const float* Wc = (const float*)d_in[10];
  const float* bc = (const float*)d_in[11];
  const float* Wo = (const float*)d_in[12];
  const float* bo = (const float*)d_in[13];

  float* out = (float*)d_out;
  float* out0 = out;            // B*V
  float* out1 = out + 2048000;  // B*H
  float* out2 = out + 2080768;  // B*L
  float* out3 = out + 2211840;  // B*H

  float* ws = (float*)d_ws;
  float* gi = ws;                  // 98304
  float* gh = gi + 98304;          // 98304
  float* cat = gh + 98304;         // 65536 (h_new | context)
  float* scores = cat + 65536;     // 131072
  float* pm = scores + 131072;     // 1024
  float* ps = pm + 1024;           // 1024
  float* pc = ps + 1024;           // 524288
  unsigned short* co_bf = (unsigned short*)(pc + 524288);  // 32768 u16

  hipLaunchKernelGGL(k1_gates, dim3(384), dim3(256), 0, stream,
                     seq, last_hidden, emb, Wih, Whh, bih, bhh, gi, gh);
  hipLaunchKernelGGL(k3_attn, dim3(16, 64), dim3(256), 0, stream,
                     enc, gi, gh, last_hidden, feed, cat, out1, out3,
                     scores, pm, ps, pc);
  hipLaunchKernelGGL(k45_ctx, dim3(64), dim3(256), 0, stream,
                     pm, ps, pc, scores, cat, out2);
  hipLaunchKernelGGL(k6_concat, dim3(1024), dim3(256), 0, stream,
                     cat, Wc, bc, co_bf);
  hipLaunchKernelGGL(k7_out, dim3(500), dim3(256), 0, stream,
                     co_bf, Wo, bo, out0);
}